// Round 3
// baseline (714.722 us; speedup 1.0000x reference)
//
#include <hip/hip_runtime.h>
#include <hip/hip_cooperative_groups.h>
#include <math.h>

namespace cg = cooperative_groups;

#define NN 768
#define DD 128
#define AA 312
#define HH 8
#define CEPS 1e-8f

struct Args {
    const float *visual, *semantic, *attribute;
    const float *Wvn, *bvn, *gvn, *betavn, *Wve1, *bve1, *Wve2, *bve2;
    const float *Wsn, *bsn, *gsn, *betasn, *Wse1, *bse1, *Wse2, *bse2;
    float *vp, *sp, *ve2, *se2;                                  // d_out regions
    float *nrm_v, *nrm_a, *simv, *sima, *ve, *se, *vpT, *spT, *WvnT, *WsnT;  // ws
};

__device__ __forceinline__ float wave_sum(float v) {
    #pragma unroll
    for (int o = 32; o; o >>= 1) v += __shfl_down(v, o, 64);
    return v;
}
__device__ __forceinline__ float wave_max(float v) {
    #pragma unroll
    for (int o = 32; o; o >>= 1) v = fmaxf(v, __shfl_down(v, o, 64));
    return v;
}

// ---------- stage bodies (256 threads/block, persistent task loops) ----------

// norms (tasks 0..383: 4 rows each over [visual;attribute]) + W transposes (384..415)
__device__ void stage_prep(const Args& a, float* smemf, int tid) {
    for (int task = blockIdx.x; task < 416; task += gridDim.x) {
        if (task < 384) {
            const int g = task * 4 + (tid >> 6);
            const int lane = tid & 63;
            if (g < NN) {
                const float* x = a.visual + (size_t)g * DD;
                float s = 0.f;
                for (int c = lane; c < DD; c += 64) { float v = x[c]; s = fmaf(v, v, s); }
                s = wave_sum(s);
                if (lane == 0) a.nrm_v[g] = sqrtf(s);
            } else {
                const float* x = a.attribute + (size_t)(g - NN) * AA;
                float s = 0.f;
                for (int c = lane; c < AA; c += 64) { float v = x[c]; s = fmaf(v, v, s); }
                s = wave_sum(s);
                if (lane == 0) a.nrm_a[g - NN] = sqrtf(s);
            }
        } else {
            const int u = task - 384;
            const float* S = (u >= 16) ? a.Wsn : a.Wvn;
            float* Dt = (u >= 16) ? a.WsnT : a.WvnT;
            const int tile = u & 15;
            const int c0 = (tile & 3) * 32, r0 = (tile >> 2) * 32;
            const int tx = tid & 31, ty = tid >> 5;
            __syncthreads();
            #pragma unroll
            for (int rr = ty; rr < 32; rr += 8)
                smemf[rr * 33 + tx] = S[(size_t)(r0 + rr) * DD + c0 + tx];
            __syncthreads();
            #pragma unroll
            for (int rr = ty; rr < 32; rr += 8)
                Dt[(size_t)(c0 + rr) * DD + r0 + tx] = smemf[tx * 33 + rr];
        }
    }
}

template <int COLS>
__device__ void gram_tile(const float* __restrict__ A, const float* __restrict__ nrm,
                          float invtemp, float* __restrict__ sim, int i0, int j0, int tid,
                          float* As, float* Bs) {
    const int tx = tid & 15, ty = tid >> 4;
    const int lr = tid >> 3, lc4 = (tid & 7) * 4;
    float acc00 = 0.f, acc01 = 0.f, acc10 = 0.f, acc11 = 0.f;
    for (int kc = 0; kc < COLS; kc += 32) {
        float4 av, bv;
        if (kc + lc4 + 4 <= COLS) {
            av = *(const float4*)(A + (size_t)(i0 + lr) * COLS + kc + lc4);
            bv = *(const float4*)(A + (size_t)(j0 + lr) * COLS + kc + lc4);
        } else {
            float ta[4], tb[4];
            #pragma unroll
            for (int l = 0; l < 4; ++l) {
                int c = kc + lc4 + l;
                ta[l] = (c < COLS) ? A[(size_t)(i0 + lr) * COLS + c] : 0.f;
                tb[l] = (c < COLS) ? A[(size_t)(j0 + lr) * COLS + c] : 0.f;
            }
            av = make_float4(ta[0], ta[1], ta[2], ta[3]);
            bv = make_float4(tb[0], tb[1], tb[2], tb[3]);
        }
        __syncthreads();
        As[(lc4 + 0) * 34 + lr] = av.x; As[(lc4 + 1) * 34 + lr] = av.y;
        As[(lc4 + 2) * 34 + lr] = av.z; As[(lc4 + 3) * 34 + lr] = av.w;
        Bs[(lc4 + 0) * 34 + lr] = bv.x; Bs[(lc4 + 1) * 34 + lr] = bv.y;
        Bs[(lc4 + 2) * 34 + lr] = bv.z; Bs[(lc4 + 3) * 34 + lr] = bv.w;
        __syncthreads();
        #pragma unroll
        for (int k = 0; k < 32; ++k) {
            float2 aa = *(const float2*)&As[k * 34 + 2 * ty];
            float2 bb = *(const float2*)&Bs[k * 34 + 2 * tx];
            acc00 = fmaf(aa.x, bb.x, acc00);
            acc01 = fmaf(aa.x, bb.y, acc01);
            acc10 = fmaf(aa.y, bb.x, acc10);
            acc11 = fmaf(aa.y, bb.y, acc11);
        }
    }
    const float ni0 = nrm[i0 + 2 * ty], ni1 = nrm[i0 + 2 * ty + 1];
    const float nj0 = nrm[j0 + 2 * tx], nj1 = nrm[j0 + 2 * tx + 1];
    float* s0 = sim + (size_t)(i0 + 2 * ty) * NN + j0 + 2 * tx;
    float* s1 = s0 + NN;
    s0[0] = acc00 / fmaxf(ni0 * nj0, CEPS) * invtemp;
    s0[1] = acc01 / fmaxf(ni0 * nj1, CEPS) * invtemp;
    s1[0] = acc10 / fmaxf(ni1 * nj0, CEPS) * invtemp;
    s1[1] = acc11 / fmaxf(ni1 * nj1, CEPS) * invtemp;
}

__device__ void stage_gram(const Args& a, float* smemf, int tid) {
    float* As = smemf;
    float* Bs = smemf + 1088;
    for (int task = blockIdx.x; task < 1152; task += gridDim.x) {
        const int z = task >= 576;
        const int rem = z ? task - 576 : task;
        const int by = rem / 24, bx = rem % 24;
        if (!z) gram_tile<DD>(a.visual, a.nrm_v, 10.f, a.simv, by * 32, bx * 32, tid, As, Bs);
        else    gram_tile<AA>(a.attribute, a.nrm_a, 10.f, a.sima, by * 32, bx * 32, tid, As, Bs);
    }
}

__device__ void softmax_row(const float* __restrict__ vr, float* __restrict__ er, int tid,
                            float* red) {
    float v0 = vr[tid], v1 = vr[tid + 256], v2 = vr[tid + 512];
    float m = wave_max(fmaxf(fmaxf(v0, v1), v2));
    if ((tid & 63) == 0) red[tid >> 6] = m;
    __syncthreads();
    m = fmaxf(fmaxf(red[0], red[1]), fmaxf(red[2], red[3]));
    float e0 = __expf(v0 - m), e1 = __expf(v1 - m), e2 = __expf(v2 - m);
    float s = wave_sum(e0 + e1 + e2);
    if ((tid & 63) == 0) red[4 + (tid >> 6)] = s;
    __syncthreads();
    s = red[4] + red[5] + red[6] + red[7];
    const float inv = 1.f / s;
    er[tid] = e0 * inv;
    er[tid + 256] = e1 * inv;
    er[tid + 512] = e2 * inv;
    __syncthreads();
}

__device__ void stage_softmax(const Args& a, float* smemf, int tid) {
    for (int task = blockIdx.x; task < 1536; task += gridDim.x) {
        const float* src = (task < NN) ? a.simv + (size_t)task * NN : a.sima + (size_t)(task - NN) * NN;
        float* dst = (task < NN) ? a.ve + (size_t)task * NN : a.se + (size_t)(task - NN) * NN;
        softmax_row(src, dst, tid, smemf);
    }
}

// out = relu(LN((Ep@P + Ex@P)@W^T + b)) + Ep@P ; 2 rows per task, 2-way k-split.
__device__ void node_pair(const float* __restrict__ P, const float* __restrict__ Ep,
                          const float* __restrict__ Ex, const float* __restrict__ WT,
                          const float* __restrict__ b, const float* __restrict__ g,
                          const float* __restrict__ beta, float* __restrict__ out,
                          float* __restrict__ outT, int i0, int tid, float* smemf) {
    float* part = smemf;                 // [s2][r2][m2][128] = 1024
    float* eps_ = smemf + 1024;          // [2][768]
    float* exs_ = smemf + 2560;          // [2][768]
    float* qs = smemf + 4096;            // [2][128]
    float* red = smemf + 4352;           // 16
    const int d = tid & 127, s = tid >> 7;
    #pragma unroll
    for (int r = 0; r < 2; ++r)
        for (int k = tid; k < NN; k += 256) {
            eps_[r * NN + k] = Ep[(size_t)(i0 + r) * NN + k];
            exs_[r * NN + k] = Ex[(size_t)(i0 + r) * NN + k];
        }
    __syncthreads();
    float p0 = 0.f, x0 = 0.f, p1 = 0.f, x1 = 0.f;
    const int kb = s * 384;
    #pragma unroll 4
    for (int kk = 0; kk < 384; ++kk) {
        const int k = kb + kk;
        const float pv = P[(size_t)k * DD + d];
        p0 = fmaf(eps_[k], pv, p0);
        x0 = fmaf(exs_[k], pv, x0);
        p1 = fmaf(eps_[NN + k], pv, p1);
        x1 = fmaf(exs_[NN + k], pv, x1);
    }
    part[((s * 2 + 0) * 2 + 0) * 128 + d] = p0;
    part[((s * 2 + 0) * 2 + 1) * 128 + d] = x0;
    part[((s * 2 + 1) * 2 + 0) * 128 + d] = p1;
    part[((s * 2 + 1) * 2 + 1) * 128 + d] = x1;
    __syncthreads();
    const int r = tid >> 7;
    float p = part[((0 * 2 + r) * 2 + 0) * 128 + d] + part[((1 * 2 + r) * 2 + 0) * 128 + d];
    float x = part[((0 * 2 + r) * 2 + 1) * 128 + d] + part[((1 * 2 + r) * 2 + 1) * 128 + d];
    qs[r * 128 + d] = p + x;
    __syncthreads();
    float t = b[d];
    #pragma unroll 4
    for (int c = 0; c < DD; ++c) t = fmaf(qs[r * 128 + c], WT[(size_t)c * DD + d], t);
    float sm = wave_sum(t);
    if ((tid & 63) == 0) red[tid >> 6] = sm;
    __syncthreads();
    const float mean = (red[2 * r] + red[2 * r + 1]) * (1.f / DD);
    const float dv = t - mean;
    float s2 = wave_sum(dv * dv);
    if ((tid & 63) == 0) red[4 + (tid >> 6)] = s2;
    __syncthreads();
    const float var = (red[4 + 2 * r] + red[4 + 2 * r + 1]) * (1.f / DD);
    const float ln = dv * rsqrtf(var + 1e-5f) * g[d] + beta[d];
    const float val = fmaxf(ln, 0.f) + p;
    out[(size_t)(i0 + r) * DD + d] = val;
    outT[(size_t)d * NN + i0 + r] = val;
    __syncthreads();
}

__device__ void stage_node(const Args& a, float* smemf, int tid, const float* P, const float* Ep,
                           const float* Ex, const float* WT, const float* b, const float* g,
                           const float* beta, float* out, float* outT) {
    for (int task = blockIdx.x; task < NN / 2; task += gridDim.x)
        node_pair(P, Ep, Ex, WT, b, g, beta, out, outT, task * 2, tid, smemf);
}

__device__ __forceinline__ float edge_mlp_tail(float* z, const float* __restrict__ b1,
                                               const float* __restrict__ W2, float b2s) {
    float mean = 0.f;
    #pragma unroll
    for (int r = 0; r < HH; ++r) { z[r] += b1[r]; mean += z[r]; }
    mean *= (1.f / HH);
    float var = 0.f;
    #pragma unroll
    for (int r = 0; r < HH; ++r) { float dv = z[r] - mean; var += dv * dv; }
    var *= (1.f / HH);
    const float istd = rsqrtf(var + 1e-5f);
    float acc = b2s;
    #pragma unroll
    for (int r = 0; r < HH; ++r) {
        float hn = fmaxf((z[r] - mean) * istd, 0.f);
        acc = fmaf(hn, W2[r], acc);
    }
    return tanhf(acc);
}

// full edge_update row (logits + row softmax), writes E2 row.
__device__ void edge_row(const float* __restrict__ PR, const float* __restrict__ PRt,
                         const float* __restrict__ lastE, const float4* w_s,
                         const float* __restrict__ b1, const float* __restrict__ W2, float b2s,
                         float invtemp, float* __restrict__ E2, int i, int tid, float* pi,
                         float* red) {
    if (tid < DD) pi[tid] = PR[(size_t)i * DD + tid];
    __syncthreads();
    const int j0 = tid, j1 = tid + 256, j2 = tid + 512;
    float z0[HH], z1[HH], z2[HH];
    #pragma unroll
    for (int r = 0; r < HH; ++r) { z0[r] = 0.f; z1[r] = 0.f; z2[r] = 0.f; }
    const float4* p4 = (const float4*)pi;
    #pragma unroll 2
    for (int k4 = 0; k4 < DD / 4; ++k4) {
        const float4 pv = p4[k4];
        const float* r0 = PRt + (size_t)(k4 * 4) * NN;
        const float* r1 = r0 + NN;
        const float* r2 = r1 + NN;
        const float* r3 = r2 + NN;
        float q00 = pv.x - r0[j0]; q00 *= q00;
        float q10 = pv.x - r0[j1]; q10 *= q10;
        float q20 = pv.x - r0[j2]; q20 *= q20;
        float q01 = pv.y - r1[j0]; q01 *= q01;
        float q11 = pv.y - r1[j1]; q11 *= q11;
        float q21 = pv.y - r1[j2]; q21 *= q21;
        float q02 = pv.z - r2[j0]; q02 *= q02;
        float q12 = pv.z - r2[j1]; q12 *= q12;
        float q22 = pv.z - r2[j2]; q22 *= q22;
        float q03 = pv.w - r3[j0]; q03 *= q03;
        float q13 = pv.w - r3[j1]; q13 *= q13;
        float q23 = pv.w - r3[j2]; q23 *= q23;
        #pragma unroll
        for (int r = 0; r < HH; ++r) {
            const float4 w = w_s[r * (DD / 4) + k4];
            z0[r] += w.x * q00 + w.y * q01 + w.z * q02 + w.w * q03;
            z1[r] += w.x * q10 + w.y * q11 + w.z * q12 + w.w * q13;
            z2[r] += w.x * q20 + w.y * q21 + w.z * q22 + w.w * q23;
        }
    }
    const float* lrow = lastE + (size_t)i * NN;
    float v0 = edge_mlp_tail(z0, b1, W2, b2s) * (lrow[j0] + CEPS) * invtemp;
    float v1 = edge_mlp_tail(z1, b1, W2, b2s) * (lrow[j1] + CEPS) * invtemp;
    float v2 = edge_mlp_tail(z2, b1, W2, b2s) * (lrow[j2] + CEPS) * invtemp;
    float m = wave_max(fmaxf(fmaxf(v0, v1), v2));
    if ((tid & 63) == 0) red[tid >> 6] = m;
    __syncthreads();
    m = fmaxf(fmaxf(red[0], red[1]), fmaxf(red[2], red[3]));
    float e0 = __expf(v0 - m), e1 = __expf(v1 - m), e2 = __expf(v2 - m);
    float s = wave_sum(e0 + e1 + e2);
    if ((tid & 63) == 0) red[4 + (tid >> 6)] = s;
    __syncthreads();
    s = red[4] + red[5] + red[6] + red[7];
    const float inv = 1.f / s;
    float* Er = E2 + (size_t)i * NN;
    Er[j0] = e0 * inv;
    Er[j1] = e1 * inv;
    Er[j2] = e2 * inv;
    __syncthreads();
}

__device__ void stage_edge(const Args& a, float* smemf, int tid, const float* PR,
                           const float* PRt, const float* lastE, const float* W1,
                           const float* b1, const float* W2, const float* b2, float invtemp,
                           float* E2) {
    float* pi = smemf;                       // 128
    float4* w_s = (float4*)(smemf + 128);    // 1024 floats
    float* red = smemf + 1152;               // 16
    w_s[tid] = ((const float4*)W1)[tid];     // 256 float4 = all of W1
    __syncthreads();
    const float b2s = b2[0];
    for (int task = blockIdx.x; task < NN; task += gridDim.x)
        edge_row(PR, PRt, lastE, w_s, b1, W2, b2s, invtemp, E2, task, tid, pi, red);
}

__device__ void run_stage(const Args& a, int stage, float* smemf, int tid) {
    switch (stage) {
        case 0: stage_prep(a, smemf, tid); break;
        case 1: stage_gram(a, smemf, tid); break;
        case 2: stage_softmax(a, smemf, tid); break;
        case 3: stage_node(a, smemf, tid, a.visual, a.ve, a.se, a.WvnT, a.bvn, a.gvn, a.betavn,
                           a.vp, a.vpT); break;
        case 4: stage_edge(a, smemf, tid, a.vp, a.vpT, a.ve, a.Wve1, a.bve1, a.Wve2, a.bve2,
                           0.1f, a.ve2); break;
        case 5: stage_node(a, smemf, tid, a.semantic, a.se, a.ve2, a.WsnT, a.bsn, a.gsn,
                           a.betasn, a.sp, a.spT); break;
        case 6: stage_edge(a, smemf, tid, a.sp, a.spT, a.se, a.Wse1, a.bse1, a.Wse2, a.bse2,
                           0.1f, a.se2); break;
    }
}

__global__ __launch_bounds__(256) void mega_kernel(Args a) {
    __shared__ __align__(16) float smemf[4384];
    const int tid = threadIdx.x;
    cg::grid_group grid = cg::this_grid();
    run_stage(a, 0, smemf, tid); grid.sync();
    run_stage(a, 1, smemf, tid); grid.sync();
    run_stage(a, 2, smemf, tid); grid.sync();
    run_stage(a, 3, smemf, tid); grid.sync();
    run_stage(a, 4, smemf, tid); grid.sync();
    run_stage(a, 5, smemf, tid); grid.sync();
    run_stage(a, 6, smemf, tid);
}

// fallback path: same device code as 7 separate launches (no grid.sync needed across kernels)
__global__ __launch_bounds__(256) void stage_kernel(Args a, int stage) {
    __shared__ __align__(16) float smemf[4384];
    run_stage(a, stage, smemf, threadIdx.x);
}

extern "C" void kernel_launch(void* const* d_in, const int* in_sizes, int n_in, void* d_out,
                              int out_size, void* d_ws, size_t ws_size, hipStream_t stream) {
    Args h;
    h.visual = (const float*)d_in[0];
    h.semantic = (const float*)d_in[1];
    h.attribute = (const float*)d_in[2];
    h.Wvn = (const float*)d_in[3];  h.bvn = (const float*)d_in[4];
    h.gvn = (const float*)d_in[5];  h.betavn = (const float*)d_in[6];
    h.Wve1 = (const float*)d_in[7]; h.bve1 = (const float*)d_in[8];
    h.Wve2 = (const float*)d_in[9]; h.bve2 = (const float*)d_in[10];
    h.Wsn = (const float*)d_in[11]; h.bsn = (const float*)d_in[12];
    h.gsn = (const float*)d_in[13]; h.betasn = (const float*)d_in[14];
    h.Wse1 = (const float*)d_in[15]; h.bse1 = (const float*)d_in[16];
    h.Wse2 = (const float*)d_in[17]; h.bse2 = (const float*)d_in[18];

    float* out = (float*)d_out;
    h.vp = out;
    h.sp = out + 98304;
    h.ve2 = out + 196608;
    h.se2 = out + 786432;

    float* ws = (float*)d_ws;
    h.nrm_v = ws;
    h.nrm_a = ws + 768;
    h.simv = ws + 1536;
    h.sima = ws + 591360;
    h.ve = ws + 1181184;
    h.se = ws + 1771008;
    h.vpT = ws + 2360832;
    h.spT = ws + 2459136;
    h.WvnT = ws + 2557440;
    h.WsnT = ws + 2573824;

    int maxb = 0;
    hipError_t qerr = hipOccupancyMaxActiveBlocksPerMultiprocessor(&maxb, mega_kernel, 256, 0);
    if (qerr != hipSuccess || maxb < 1) maxb = 1;
    if (maxb > 2) maxb = 2;
    const int grid = 256 * maxb;

    void* params[] = {(void*)&h};
    hipError_t lerr = hipLaunchCooperativeKernel((const void*)mega_kernel, dim3(grid), dim3(256),
                                                 params, 0u, stream);
    if (lerr != hipSuccess) {
        // fallback: sequential stage kernels (stream order provides the dependencies)
        for (int s = 0; s < 7; ++s)
            stage_kernel<<<dim3(512), dim3(256), 0, stream>>>(h, s);
    }
}

// Round 4
// 229.084 us; speedup vs baseline: 3.1199x; 3.1199x over previous
//
#include <hip/hip_runtime.h>
#include <math.h>

#define NN 768
#define DD 128
#define AA 312
#define HH 8
#define CEPS 1e-8f

__device__ __forceinline__ float wave_sum(float v) {
    #pragma unroll
    for (int o = 32; o; o >>= 1) v += __shfl_down(v, o, 64);
    return v;
}
__device__ __forceinline__ float wave_max(float v) {
    #pragma unroll
    for (int o = 32; o; o >>= 1) v = fmaxf(v, __shfl_down(v, o, 64));
    return v;
}

// ---------------- K1: gram logits (inline row norms) + W transposes ----------------
// sim[i][j] = dot(A_i,A_j)/max(|A_i||A_j|,eps) * invtemp   (raw logits, softmax deferred)
template <int COLS>
__device__ void gram_tile(const float* __restrict__ A, float invtemp, float* __restrict__ sim,
                          int i0, int j0, int tid, float* As, float* Bs) {
    const int tx = tid & 15, ty = tid >> 4;
    const int lr = tid >> 3, lc4 = (tid & 7) * 4;
    float acc00 = 0.f, acc01 = 0.f, acc10 = 0.f, acc11 = 0.f;
    float si0 = 0.f, si1 = 0.f, sj0 = 0.f, sj1 = 0.f;  // inline row sumsq (redundant but exact)
    for (int kc = 0; kc < COLS; kc += 32) {
        float4 av, bv;
        if (kc + lc4 + 4 <= COLS) {
            av = *(const float4*)(A + (size_t)(i0 + lr) * COLS + kc + lc4);
            bv = *(const float4*)(A + (size_t)(j0 + lr) * COLS + kc + lc4);
        } else {
            float ta[4], tb[4];
            #pragma unroll
            for (int l = 0; l < 4; ++l) {
                int c = kc + lc4 + l;
                ta[l] = (c < COLS) ? A[(size_t)(i0 + lr) * COLS + c] : 0.f;
                tb[l] = (c < COLS) ? A[(size_t)(j0 + lr) * COLS + c] : 0.f;
            }
            av = make_float4(ta[0], ta[1], ta[2], ta[3]);
            bv = make_float4(tb[0], tb[1], tb[2], tb[3]);
        }
        __syncthreads();
        As[(lc4 + 0) * 34 + lr] = av.x; As[(lc4 + 1) * 34 + lr] = av.y;
        As[(lc4 + 2) * 34 + lr] = av.z; As[(lc4 + 3) * 34 + lr] = av.w;
        Bs[(lc4 + 0) * 34 + lr] = bv.x; Bs[(lc4 + 1) * 34 + lr] = bv.y;
        Bs[(lc4 + 2) * 34 + lr] = bv.z; Bs[(lc4 + 3) * 34 + lr] = bv.w;
        __syncthreads();
        #pragma unroll
        for (int k = 0; k < 32; ++k) {
            float2 aa = *(const float2*)&As[k * 34 + 2 * ty];
            float2 bb = *(const float2*)&Bs[k * 34 + 2 * tx];
            acc00 = fmaf(aa.x, bb.x, acc00);
            acc01 = fmaf(aa.x, bb.y, acc01);
            acc10 = fmaf(aa.y, bb.x, acc10);
            acc11 = fmaf(aa.y, bb.y, acc11);
            si0 = fmaf(aa.x, aa.x, si0);
            si1 = fmaf(aa.y, aa.y, si1);
            sj0 = fmaf(bb.x, bb.x, sj0);
            sj1 = fmaf(bb.y, bb.y, sj1);
        }
    }
    const float ni0 = sqrtf(si0), ni1 = sqrtf(si1);
    const float nj0 = sqrtf(sj0), nj1 = sqrtf(sj1);
    float* s0 = sim + (size_t)(i0 + 2 * ty) * NN + j0 + 2 * tx;
    float* s1 = s0 + NN;
    s0[0] = acc00 / fmaxf(ni0 * nj0, CEPS) * invtemp;
    s0[1] = acc01 / fmaxf(ni0 * nj1, CEPS) * invtemp;
    s1[0] = acc10 / fmaxf(ni1 * nj0, CEPS) * invtemp;
    s1[1] = acc11 / fmaxf(ni1 * nj1, CEPS) * invtemp;
}

__global__ __launch_bounds__(256) void gram_prep_kernel(
    const float* __restrict__ visual, const float* __restrict__ attribute,
    const float* __restrict__ Wvn, const float* __restrict__ Wsn, float* __restrict__ simv,
    float* __restrict__ sima, float* __restrict__ WvnT, float* __restrict__ WsnT) {
    __shared__ __align__(16) float smem[2176];
    const int tid = threadIdx.x;
    const int task = blockIdx.x;
    if (task < 576) {
        gram_tile<DD>(visual, 10.f, simv, (task / 24) * 32, (task % 24) * 32, tid, smem,
                      smem + 1088);
    } else if (task < 1152) {
        const int rem = task - 576;
        gram_tile<AA>(attribute, 10.f, sima, (rem / 24) * 32, (rem % 24) * 32, tid, smem,
                      smem + 1088);
    } else {
        const int u = task - 1152;
        const float* S = (u >= 16) ? Wsn : Wvn;
        float* Dt = (u >= 16) ? WsnT : WvnT;
        const int tile = u & 15;
        const int c0 = (tile & 3) * 32, r0 = (tile >> 2) * 32;
        const int tx = tid & 31, ty = tid >> 5;
        #pragma unroll
        for (int rr = ty; rr < 32; rr += 8)
            smem[rr * 33 + tx] = S[(size_t)(r0 + rr) * DD + c0 + tx];
        __syncthreads();
        #pragma unroll
        for (int rr = ty; rr < 32; rr += 8)
            Dt[(size_t)(c0 + rr) * DD + r0 + tx] = smem[tx * 33 + rr];
    }
}

// block-wide softmax (512 threads) over a 768-float LDS buffer, in place.
__device__ void block_softmax768(float* buf, int tid, float* red) {
    const int w = tid >> 6, lane = tid & 63;
    float v0 = buf[tid];
    float v1 = (tid < NN - 512) ? buf[tid + 512] : -3.4e38f;
    float m = wave_max(fmaxf(v0, v1));
    if (lane == 0) red[w] = m;
    __syncthreads();
    m = red[0];
    #pragma unroll
    for (int i = 1; i < 8; ++i) m = fmaxf(m, red[i]);
    float e0 = __expf(v0 - m);
    float e1 = (tid < NN - 512) ? __expf(v1 - m) : 0.f;
    float sw = wave_sum(e0 + e1);
    if (lane == 0) red[8 + w] = sw;
    __syncthreads();
    float s = 0.f;
    #pragma unroll
    for (int i = 0; i < 8; ++i) s += red[8 + i];
    const float inv = 1.f / s;
    buf[tid] = e0 * inv;
    if (tid < NN - 512) buf[tid + 512] = e1 * inv;
    __syncthreads();
}

// ---------------- K2/K4: node update, softmax-on-the-fly ----------------
// out = relu(LN((Ep@P + Ex@P)@W^T + b)) + Ep@P ; 2 rows/block, 512 thr, 4-way k-split.
template <bool EX_SM>
__global__ __launch_bounds__(512) void node_kernel(
    const float* __restrict__ P, const float* __restrict__ srcEp,
    const float* __restrict__ srcEx, const float* __restrict__ WT, const float* __restrict__ b,
    const float* __restrict__ g, const float* __restrict__ beta, float* __restrict__ out,
    float* __restrict__ outT) {
    __shared__ float ep[2][NN], ex[2][NN];
    __shared__ float pp[4][2][DD], xx[4][2][DD];
    __shared__ float qs[2][DD], tps[2][2][DD];
    __shared__ float red[16];
    const int i0 = blockIdx.x * 2;
    const int tid = threadIdx.x;
    const int s = tid >> 7 & 3, d = tid & 127;
    #pragma unroll
    for (int r = 0; r < 2; ++r)
        for (int k = tid; k < NN; k += 512) {
            ep[r][k] = srcEp[(size_t)(i0 + r) * NN + k];
            ex[r][k] = srcEx[(size_t)(i0 + r) * NN + k];
        }
    __syncthreads();
    block_softmax768(ep[0], tid, red);
    block_softmax768(ep[1], tid, red);
    if (EX_SM) {
        block_softmax768(ex[0], tid, red);
        block_softmax768(ex[1], tid, red);
    }
    float p0 = 0.f, x0 = 0.f, p1 = 0.f, x1 = 0.f;
    const int kb = s * 192;
    #pragma unroll 4
    for (int kk = 0; kk < 192; ++kk) {
        const int k = kb + kk;
        const float pv = P[(size_t)k * DD + d];
        p0 = fmaf(ep[0][k], pv, p0);
        x0 = fmaf(ex[0][k], pv, x0);
        p1 = fmaf(ep[1][k], pv, p1);
        x1 = fmaf(ex[1][k], pv, x1);
    }
    pp[s][0][d] = p0; xx[s][0][d] = x0;
    pp[s][1][d] = p1; xx[s][1][d] = x1;
    __syncthreads();
    const int rr = (tid >> 7) & 1;
    float preg = 0.f;
    if (tid < 256) {
        float p = pp[0][rr][d] + pp[1][rr][d] + pp[2][rr][d] + pp[3][rr][d];
        float x = xx[0][rr][d] + xx[1][rr][d] + xx[2][rr][d] + xx[3][rr][d];
        qs[rr][d] = p + x;
        preg = p;
    }
    __syncthreads();
    {
        const int sc = tid >> 8, rr2 = (tid >> 7) & 1;
        float t = (sc == 0) ? b[d] : 0.f;
        const int c0 = sc * 64;
        #pragma unroll 4
        for (int c = c0; c < c0 + 64; ++c) t = fmaf(qs[rr2][c], WT[(size_t)c * DD + d], t);
        tps[sc][rr2][d] = t;
    }
    __syncthreads();
    float tval = 0.f;
    if (tid < 256) tval = tps[0][rr][d] + tps[1][rr][d];
    float sm = wave_sum(tid < 256 ? tval : 0.f);
    if ((tid & 63) == 0) red[tid >> 6] = sm;
    __syncthreads();
    if (tid < 256) tval -= (red[2 * rr] + red[2 * rr + 1]) * (1.f / DD);
    float s2 = wave_sum(tid < 256 ? tval * tval : 0.f);
    if ((tid & 63) == 0) red[8 + (tid >> 6)] = s2;
    __syncthreads();
    if (tid < 256) {
        const float var = (red[8 + 2 * rr] + red[8 + 2 * rr + 1]) * (1.f / DD);
        const float ln = tval * rsqrtf(var + 1e-5f) * g[d] + beta[d];
        const float val = fmaxf(ln, 0.f) + preg;
        out[(size_t)(i0 + rr) * DD + d] = val;
        outT[(size_t)d * NN + i0 + rr] = val;
    }
}

__device__ __forceinline__ float edge_mlp_tail(float* z, const float* __restrict__ b1,
                                               const float* __restrict__ W2, float b2s) {
    float mean = 0.f;
    #pragma unroll
    for (int r = 0; r < HH; ++r) { z[r] += b1[r]; mean += z[r]; }
    mean *= (1.f / HH);
    float var = 0.f;
    #pragma unroll
    for (int r = 0; r < HH; ++r) { float dv = z[r] - mean; var += dv * dv; }
    var *= (1.f / HH);
    const float istd = rsqrtf(var + 1e-5f);
    float acc = b2s;
    #pragma unroll
    for (int r = 0; r < HH; ++r) {
        float hn = fmaxf((z[r] - mean) * istd, 0.f);
        acc = fmaf(hn, W2[r], acc);
    }
    return tanhf(acc);
}

// ---------------- K3/K5: edge update, lastE softmax-on-the-fly ----------------
__global__ __launch_bounds__(256) void edge_kernel(
    const float* __restrict__ PR, const float* __restrict__ PRt,
    const float* __restrict__ lastSim, const float* __restrict__ W1,
    const float* __restrict__ b1, const float* __restrict__ W2, const float* __restrict__ b2,
    float invtemp, float* __restrict__ E2) {
    const int i = blockIdx.x;
    const int tid = threadIdx.x;
    __shared__ float pi[DD];
    __shared__ __align__(16) float4 w_s[HH][DD / 4];
    __shared__ float lrow[NN];
    __shared__ float red[16];
    if (tid < DD) pi[tid] = PR[(size_t)i * DD + tid];
    ((float4*)w_s)[tid] = ((const float4*)W1)[tid];  // all of W1
    // softmax(lastSim row i) -> lrow
    {
        const float* vr = lastSim + (size_t)i * NN;
        float v0 = vr[tid], v1 = vr[tid + 256], v2 = vr[tid + 512];
        float m = wave_max(fmaxf(fmaxf(v0, v1), v2));
        if ((tid & 63) == 0) red[tid >> 6] = m;
        __syncthreads();
        m = fmaxf(fmaxf(red[0], red[1]), fmaxf(red[2], red[3]));
        float e0 = __expf(v0 - m), e1 = __expf(v1 - m), e2 = __expf(v2 - m);
        float sw = wave_sum(e0 + e1 + e2);
        if ((tid & 63) == 0) red[4 + (tid >> 6)] = sw;
        __syncthreads();
        const float s = red[4] + red[5] + red[6] + red[7];
        const float inv = 1.f / s;
        lrow[tid] = e0 * inv;
        lrow[tid + 256] = e1 * inv;
        lrow[tid + 512] = e2 * inv;
        __syncthreads();
    }
    const int j0 = tid, j1 = tid + 256, j2 = tid + 512;
    float z0[HH], z1[HH], z2[HH];
    #pragma unroll
    for (int r = 0; r < HH; ++r) { z0[r] = 0.f; z1[r] = 0.f; z2[r] = 0.f; }
    const float4* p4 = (const float4*)pi;
    #pragma unroll 2
    for (int k4 = 0; k4 < DD / 4; ++k4) {
        const float4 pv = p4[k4];
        const float* r0 = PRt + (size_t)(k4 * 4) * NN;
        const float* r1 = r0 + NN;
        const float* r2 = r1 + NN;
        const float* r3 = r2 + NN;
        float q00 = pv.x - r0[j0]; q00 *= q00;
        float q10 = pv.x - r0[j1]; q10 *= q10;
        float q20 = pv.x - r0[j2]; q20 *= q20;
        float q01 = pv.y - r1[j0]; q01 *= q01;
        float q11 = pv.y - r1[j1]; q11 *= q11;
        float q21 = pv.y - r1[j2]; q21 *= q21;
        float q02 = pv.z - r2[j0]; q02 *= q02;
        float q12 = pv.z - r2[j1]; q12 *= q12;
        float q22 = pv.z - r2[j2]; q22 *= q22;
        float q03 = pv.w - r3[j0]; q03 *= q03;
        float q13 = pv.w - r3[j1]; q13 *= q13;
        float q23 = pv.w - r3[j2]; q23 *= q23;
        #pragma unroll
        for (int r = 0; r < HH; ++r) {
            const float4 w = w_s[r][k4];
            z0[r] += w.x * q00 + w.y * q01 + w.z * q02 + w.w * q03;
            z1[r] += w.x * q10 + w.y * q11 + w.z * q12 + w.w * q13;
            z2[r] += w.x * q20 + w.y * q21 + w.z * q22 + w.w * q23;
        }
    }
    const float b2s = b2[0];
    float v0 = edge_mlp_tail(z0, b1, W2, b2s) * (lrow[j0] + CEPS) * invtemp;
    float v1 = edge_mlp_tail(z1, b1, W2, b2s) * (lrow[j1] + CEPS) * invtemp;
    float v2 = edge_mlp_tail(z2, b1, W2, b2s) * (lrow[j2] + CEPS) * invtemp;
    float m = wave_max(fmaxf(fmaxf(v0, v1), v2));
    if ((tid & 63) == 0) red[tid >> 6] = m;
    __syncthreads();
    m = fmaxf(fmaxf(red[0], red[1]), fmaxf(red[2], red[3]));
    float e0 = __expf(v0 - m), e1 = __expf(v1 - m), e2 = __expf(v2 - m);
    float sw = wave_sum(e0 + e1 + e2);
    if ((tid & 63) == 0) red[4 + (tid >> 6)] = sw;
    __syncthreads();
    const float s = red[4] + red[5] + red[6] + red[7];
    const float inv = 1.f / s;
    float* Er = E2 + (size_t)i * NN;
    Er[j0] = e0 * inv;
    Er[j1] = e1 * inv;
    Er[j2] = e2 * inv;
}

extern "C" void kernel_launch(void* const* d_in, const int* in_sizes, int n_in, void* d_out,
                              int out_size, void* d_ws, size_t ws_size, hipStream_t stream) {
    const float* visual    = (const float*)d_in[0];
    const float* semantic  = (const float*)d_in[1];
    const float* attribute = (const float*)d_in[2];
    const float* Wvn  = (const float*)d_in[3];
    const float* bvn  = (const float*)d_in[4];
    const float* gvn  = (const float*)d_in[5];
    const float* betavn = (const float*)d_in[6];
    const float* Wve1 = (const float*)d_in[7];
    const float* bve1 = (const float*)d_in[8];
    const float* Wve2 = (const float*)d_in[9];
    const float* bve2 = (const float*)d_in[10];
    const float* Wsn  = (const float*)d_in[11];
    const float* bsn  = (const float*)d_in[12];
    const float* gsn  = (const float*)d_in[13];
    const float* betasn = (const float*)d_in[14];
    const float* Wse1 = (const float*)d_in[15];
    const float* bse1 = (const float*)d_in[16];
    const float* Wse2 = (const float*)d_in[17];
    const float* bse2 = (const float*)d_in[18];

    float* out = (float*)d_out;
    float* vp  = out;              // 768*128
    float* sp  = out + 98304;      // 768*128
    float* ve2 = out + 196608;     // 768*768
    float* se2 = out + 786432;     // 768*768

    float* ws   = (float*)d_ws;
    float* simv = ws;              // 768*768 raw logits (already /temp)
    float* sima = ws + 589824;     // 768*768
    float* vpT  = ws + 1179648;    // 128*768
    float* spT  = ws + 1277952;    // 128*768
    float* WvnT = ws + 1376256;    // 128*128
    float* WsnT = ws + 1392640;    // 128*128

    gram_prep_kernel<<<1184, 256, 0, stream>>>(visual, attribute, Wvn, Wsn, simv, sima, WvnT,
                                               WsnT);
    node_kernel<true><<<NN / 2, 512, 0, stream>>>(visual, simv, sima, WvnT, bvn, gvn, betavn,
                                                  vp, vpT);
    edge_kernel<<<NN, 256, 0, stream>>>(vp, vpT, simv, Wve1, bve1, Wve2, bve2, 0.1f, ve2);
    node_kernel<false><<<NN / 2, 512, 0, stream>>>(semantic, sima, ve2, WsnT, bsn, gsn, betasn,
                                                   sp, spT);
    edge_kernel<<<NN, 256, 0, stream>>>(sp, spT, sima, Wse1, bse1, Wse2, bse2, 0.1f, se2);
}

// Round 5
// 197.287 us; speedup vs baseline: 3.6228x; 1.1612x over previous
//
#include <hip/hip_runtime.h>
#include <math.h>

#define NN 768
#define DD 128
#define AA 312
#define HH 8
#define CEPS 1e-8f

typedef __attribute__((ext_vector_type(2))) float v2f;

__device__ __forceinline__ v2f vfma2(v2f a, v2f b, v2f c) {
#if __has_builtin(__builtin_elementwise_fma)
    return __builtin_elementwise_fma(a, b, c);
#else
    v2f r;
    r.x = fmaf(a.x, b.x, c.x);
    r.y = fmaf(a.y, b.y, c.y);
    return r;
#endif
}

__device__ __forceinline__ float wave_sum(float v) {
    #pragma unroll
    for (int o = 32; o; o >>= 1) v += __shfl_down(v, o, 64);
    return v;
}
__device__ __forceinline__ float wave_max(float v) {
    #pragma unroll
    for (int o = 32; o; o >>= 1) v = fmaxf(v, __shfl_down(v, o, 64));
    return v;
}

// ---------------- K1: gram logits (inline row norms) + W transposes ----------------
template <int COLS>
__device__ void gram_tile(const float* __restrict__ A, float invtemp, float* __restrict__ sim,
                          int i0, int j0, int tid, float* As, float* Bs) {
    const int tx = tid & 15, ty = tid >> 4;
    const int lr = tid >> 3, lc4 = (tid & 7) * 4;
    float acc00 = 0.f, acc01 = 0.f, acc10 = 0.f, acc11 = 0.f;
    float si0 = 0.f, si1 = 0.f, sj0 = 0.f, sj1 = 0.f;
    for (int kc = 0; kc < COLS; kc += 32) {
        float4 av, bv;
        if (kc + lc4 + 4 <= COLS) {
            av = *(const float4*)(A + (size_t)(i0 + lr) * COLS + kc + lc4);
            bv = *(const float4*)(A + (size_t)(j0 + lr) * COLS + kc + lc4);
        } else {
            float ta[4], tb[4];
            #pragma unroll
            for (int l = 0; l < 4; ++l) {
                int c = kc + lc4 + l;
                ta[l] = (c < COLS) ? A[(size_t)(i0 + lr) * COLS + c] : 0.f;
                tb[l] = (c < COLS) ? A[(size_t)(j0 + lr) * COLS + c] : 0.f;
            }
            av = make_float4(ta[0], ta[1], ta[2], ta[3]);
            bv = make_float4(tb[0], tb[1], tb[2], tb[3]);
        }
        __syncthreads();
        As[(lc4 + 0) * 34 + lr] = av.x; As[(lc4 + 1) * 34 + lr] = av.y;
        As[(lc4 + 2) * 34 + lr] = av.z; As[(lc4 + 3) * 34 + lr] = av.w;
        Bs[(lc4 + 0) * 34 + lr] = bv.x; Bs[(lc4 + 1) * 34 + lr] = bv.y;
        Bs[(lc4 + 2) * 34 + lr] = bv.z; Bs[(lc4 + 3) * 34 + lr] = bv.w;
        __syncthreads();
        #pragma unroll
        for (int k = 0; k < 32; ++k) {
            float2 aa = *(const float2*)&As[k * 34 + 2 * ty];
            float2 bb = *(const float2*)&Bs[k * 34 + 2 * tx];
            acc00 = fmaf(aa.x, bb.x, acc00);
            acc01 = fmaf(aa.x, bb.y, acc01);
            acc10 = fmaf(aa.y, bb.x, acc10);
            acc11 = fmaf(aa.y, bb.y, acc11);
            si0 = fmaf(aa.x, aa.x, si0);
            si1 = fmaf(aa.y, aa.y, si1);
            sj0 = fmaf(bb.x, bb.x, sj0);
            sj1 = fmaf(bb.y, bb.y, sj1);
        }
    }
    const float ni0 = sqrtf(si0), ni1 = sqrtf(si1);
    const float nj0 = sqrtf(sj0), nj1 = sqrtf(sj1);
    float* s0 = sim + (size_t)(i0 + 2 * ty) * NN + j0 + 2 * tx;
    float* s1 = s0 + NN;
    s0[0] = acc00 / fmaxf(ni0 * nj0, CEPS) * invtemp;
    s0[1] = acc01 / fmaxf(ni0 * nj1, CEPS) * invtemp;
    s1[0] = acc10 / fmaxf(ni1 * nj0, CEPS) * invtemp;
    s1[1] = acc11 / fmaxf(ni1 * nj1, CEPS) * invtemp;
}

__global__ __launch_bounds__(256) void gram_prep_kernel(
    const float* __restrict__ visual, const float* __restrict__ attribute,
    const float* __restrict__ Wvn, const float* __restrict__ Wsn, float* __restrict__ simv,
    float* __restrict__ sima, float* __restrict__ WvnT, float* __restrict__ WsnT) {
    __shared__ __align__(16) float smem[2176];
    const int tid = threadIdx.x;
    const int task = blockIdx.x;
    if (task < 576) {
        gram_tile<DD>(visual, 10.f, simv, (task / 24) * 32, (task % 24) * 32, tid, smem,
                      smem + 1088);
    } else if (task < 1152) {
        const int rem = task - 576;
        gram_tile<AA>(attribute, 10.f, sima, (rem / 24) * 32, (rem % 24) * 32, tid, smem,
                      smem + 1088);
    } else {
        const int u = task - 1152;
        const float* S = (u >= 16) ? Wsn : Wvn;
        float* Dt = (u >= 16) ? WsnT : WvnT;
        const int tile = u & 15;
        const int c0 = (tile & 3) * 32, r0 = (tile >> 2) * 32;
        const int tx = tid & 31, ty = tid >> 5;
        #pragma unroll
        for (int rr = ty; rr < 32; rr += 8)
            smem[rr * 33 + tx] = S[(size_t)(r0 + rr) * DD + c0 + tx];
        __syncthreads();
        #pragma unroll
        for (int rr = ty; rr < 32; rr += 8)
            Dt[(size_t)(c0 + rr) * DD + r0 + tx] = smem[tx * 33 + rr];
    }
}

// block-wide softmax (512 threads) over a 768-float LDS buffer, in place.
__device__ void block_softmax768(float* buf, int tid, float* red) {
    const int w = tid >> 6, lane = tid & 63;
    float v0 = buf[tid];
    float v1 = (tid < NN - 512) ? buf[tid + 512] : -3.4e38f;
    float m = wave_max(fmaxf(v0, v1));
    if (lane == 0) red[w] = m;
    __syncthreads();
    m = red[0];
    #pragma unroll
    for (int i = 1; i < 8; ++i) m = fmaxf(m, red[i]);
    float e0 = __expf(v0 - m);
    float e1 = (tid < NN - 512) ? __expf(v1 - m) : 0.f;
    float sw = wave_sum(e0 + e1);
    if (lane == 0) red[8 + w] = sw;
    __syncthreads();
    float s = 0.f;
    #pragma unroll
    for (int i = 0; i < 8; ++i) s += red[8 + i];
    const float inv = 1.f / s;
    buf[tid] = e0 * inv;
    if (tid < NN - 512) buf[tid + 512] = e1 * inv;
    __syncthreads();
}

// softmax of a global 768-row into an LDS buffer (256 threads).
__device__ void softmax_row_to(const float* __restrict__ vr, float* __restrict__ dst, int tid,
                               float* red) {
    float v0 = vr[tid], v1 = vr[tid + 256], v2 = vr[tid + 512];
    float m = wave_max(fmaxf(fmaxf(v0, v1), v2));
    if ((tid & 63) == 0) red[tid >> 6] = m;
    __syncthreads();
    m = fmaxf(fmaxf(red[0], red[1]), fmaxf(red[2], red[3]));
    float e0 = __expf(v0 - m), e1 = __expf(v1 - m), e2 = __expf(v2 - m);
    float sw = wave_sum(e0 + e1 + e2);
    if ((tid & 63) == 0) red[4 + (tid >> 6)] = sw;
    __syncthreads();
    const float s = red[4] + red[5] + red[6] + red[7];
    const float inv = 1.f / s;
    dst[tid] = e0 * inv;
    dst[tid + 256] = e1 * inv;
    dst[tid + 512] = e2 * inv;
    __syncthreads();
}

// ---------------- K2: node1 (vp), softmax-on-the-fly, packed-f32 ----------------
__global__ __launch_bounds__(512) void node1_kernel(
    const float* __restrict__ P, const float* __restrict__ srcEp,
    const float* __restrict__ srcEx, const float* __restrict__ WT, const float* __restrict__ b,
    const float* __restrict__ g, const float* __restrict__ beta, float* __restrict__ out,
    float* __restrict__ outT) {
    __shared__ __align__(16) float ep[2][NN], ex[2][NN];
    __shared__ __align__(16) float pp[4][2][DD], xx[4][2][DD];
    __shared__ __align__(16) float qs[2][DD], tps[2][2][DD];
    __shared__ float red[16];
    const int i0 = blockIdx.x * 2;
    const int tid = threadIdx.x;
    const int s = (tid >> 7) & 3, d = tid & 127;
    #pragma unroll
    for (int r = 0; r < 2; ++r)
        for (int k = tid; k < NN; k += 512) {
            ep[r][k] = srcEp[(size_t)(i0 + r) * NN + k];
            ex[r][k] = srcEx[(size_t)(i0 + r) * NN + k];
        }
    __syncthreads();
    block_softmax768(ep[0], tid, red);
    block_softmax768(ep[1], tid, red);
    block_softmax768(ex[0], tid, red);
    block_softmax768(ex[1], tid, red);
    v2f P0 = {0.f, 0.f}, X0 = {0.f, 0.f}, P1 = {0.f, 0.f}, X1 = {0.f, 0.f};
    const int kb = s * 192;
    #pragma unroll 4
    for (int kk = 0; kk < 192; kk += 2) {
        const int k = kb + kk;
        const float a0 = P[(size_t)k * DD + d];
        const float a1 = P[(size_t)(k + 1) * DD + d];
        v2f pv; pv.x = a0; pv.y = a1;
        const v2f e0v = *(const v2f*)&ep[0][k];
        const v2f x0v = *(const v2f*)&ex[0][k];
        const v2f e1v = *(const v2f*)&ep[1][k];
        const v2f x1v = *(const v2f*)&ex[1][k];
        P0 = vfma2(e0v, pv, P0);
        X0 = vfma2(x0v, pv, X0);
        P1 = vfma2(e1v, pv, P1);
        X1 = vfma2(x1v, pv, X1);
    }
    pp[s][0][d] = P0.x + P0.y; xx[s][0][d] = X0.x + X0.y;
    pp[s][1][d] = P1.x + P1.y; xx[s][1][d] = X1.x + X1.y;
    __syncthreads();
    const int rr = (tid >> 7) & 1;
    float preg = 0.f;
    if (tid < 256) {
        float p = pp[0][rr][d] + pp[1][rr][d] + pp[2][rr][d] + pp[3][rr][d];
        float x = xx[0][rr][d] + xx[1][rr][d] + xx[2][rr][d] + xx[3][rr][d];
        qs[rr][d] = p + x;
        preg = p;
    }
    __syncthreads();
    {
        const int sc = tid >> 8, rr2 = (tid >> 7) & 1;
        v2f acc; acc.x = (sc == 0) ? b[d] : 0.f; acc.y = 0.f;
        const int c0 = sc * 64;
        #pragma unroll 4
        for (int c = c0; c < c0 + 64; c += 2) {
            v2f wv; wv.x = WT[(size_t)c * DD + d]; wv.y = WT[(size_t)(c + 1) * DD + d];
            const v2f qq = *(const v2f*)&qs[rr2][c];
            acc = vfma2(qq, wv, acc);
        }
        tps[sc][rr2][d] = acc.x + acc.y;
    }
    __syncthreads();
    float tval = 0.f;
    if (tid < 256) tval = tps[0][rr][d] + tps[1][rr][d];
    float sm = wave_sum(tid < 256 ? tval : 0.f);
    if ((tid & 63) == 0) red[tid >> 6] = sm;
    __syncthreads();
    if (tid < 256) tval -= (red[2 * rr] + red[2 * rr + 1]) * (1.f / DD);
    float s2 = wave_sum(tid < 256 ? tval * tval : 0.f);
    if ((tid & 63) == 0) red[8 + (tid >> 6)] = s2;
    __syncthreads();
    if (tid < 256) {
        const float var = (red[8 + 2 * rr] + red[8 + 2 * rr + 1]) * (1.f / DD);
        const float ln = tval * rsqrtf(var + 1e-5f) * g[d] + beta[d];
        const float val = fmaxf(ln, 0.f) + preg;
        out[(size_t)(i0 + rr) * DD + d] = val;
        outT[(size_t)d * NN + i0 + rr] = val;
    }
}

__device__ __forceinline__ float edge_mlp_tail(float* z, const float* __restrict__ b1,
                                               const float* __restrict__ W2, float b2s) {
    float mean = 0.f;
    #pragma unroll
    for (int r = 0; r < HH; ++r) { z[r] += b1[r]; mean += z[r]; }
    mean *= (1.f / HH);
    float var = 0.f;
    #pragma unroll
    for (int r = 0; r < HH; ++r) { float dv = z[r] - mean; var += dv * dv; }
    var *= (1.f / HH);
    const float istd = rsqrtf(var + 1e-5f);
    float acc = b2s;
    #pragma unroll
    for (int r = 0; r < HH; ++r) {
        float hn = fmaxf((z[r] - mean) * istd, 0.f);
        acc = fmaf(hn, W2[r], acc);
    }
    return tanhf(acc);
}

// ---------------- K3/K4: edge update (packed-f32), optionally fused with next node ----------------
// FUSE: block i also computes sp row i = relu(LN((se_i@S + ve2_i@S)@Wsn^T + b)) + se_i@S.
template <bool FUSE>
__global__ __launch_bounds__(256) void edge_fused_kernel(
    const float* __restrict__ PR, const float* __restrict__ PRt,
    const float* __restrict__ lastSim, const float* __restrict__ W1,
    const float* __restrict__ b1, const float* __restrict__ W2, const float* __restrict__ b2,
    float invtemp, float* __restrict__ E2,
    // node-fusion args
    const float* __restrict__ simaRows, const float* __restrict__ S,
    const float* __restrict__ WT, const float* __restrict__ nb, const float* __restrict__ ng,
    const float* __restrict__ nbeta, float* __restrict__ outN, float* __restrict__ outNT) {
    const int i = blockIdx.x;
    const int tid = threadIdx.x;
    __shared__ __align__(16) float pi[DD];
    __shared__ __align__(16) float4 w_s[HH][DD / 4];
    __shared__ __align__(16) float lrow[NN];
    __shared__ __align__(16) float aux[NN];     // se row (FUSE)
    __shared__ __align__(16) float ve2row[NN];  // ve2 row (FUSE)
    __shared__ __align__(16) float part[4][DD];
    __shared__ __align__(16) float qvv[DD];
    __shared__ float red[16];
    if (tid < DD) pi[tid] = PR[(size_t)i * DD + tid];
    ((float4*)w_s)[tid] = ((const float4*)W1)[tid];
    softmax_row_to(lastSim + (size_t)i * NN, lrow, tid, red);  // includes syncthreads
    if (FUSE) softmax_row_to(simaRows + (size_t)i * NN, aux, tid, red);
    const int j0 = tid, j1 = tid + 256, j2 = tid + 512;
    v2f z0[HH], z1[HH], z2[HH];
    #pragma unroll
    for (int r = 0; r < HH; ++r) {
        z0[r] = (v2f){0.f, 0.f}; z1[r] = (v2f){0.f, 0.f}; z2[r] = (v2f){0.f, 0.f};
    }
    const float4* p4 = (const float4*)pi;
    for (int k4 = 0; k4 < DD / 4; ++k4) {
        const float4 pv4 = p4[k4];
        v2f pa; pa.x = pv4.x; pa.y = pv4.y;
        v2f pb; pb.x = pv4.z; pb.y = pv4.w;
        const float* r0 = PRt + (size_t)(k4 * 4) * NN;
        const float* r1 = r0 + NN;
        const float* r2 = r1 + NN;
        const float* r3 = r2 + NN;
        v2f ja0, jb0, ja1, jb1, ja2, jb2;
        ja0.x = r0[j0]; ja0.y = r1[j0]; jb0.x = r2[j0]; jb0.y = r3[j0];
        ja1.x = r0[j1]; ja1.y = r1[j1]; jb1.x = r2[j1]; jb1.y = r3[j1];
        ja2.x = r0[j2]; ja2.y = r1[j2]; jb2.x = r2[j2]; jb2.y = r3[j2];
        v2f da0 = pa - ja0, db0 = pb - jb0;
        v2f da1 = pa - ja1, db1 = pb - jb1;
        v2f da2 = pa - ja2, db2 = pb - jb2;
        v2f sa0 = da0 * da0, sb0 = db0 * db0;
        v2f sa1 = da1 * da1, sb1 = db1 * db1;
        v2f sa2 = da2 * da2, sb2 = db2 * db2;
        #pragma unroll
        for (int r = 0; r < HH; ++r) {
            const float4 w = w_s[r][k4];
            v2f wa; wa.x = w.x; wa.y = w.y;
            v2f wb; wb.x = w.z; wb.y = w.w;
            z0[r] = vfma2(wa, sa0, z0[r]); z0[r] = vfma2(wb, sb0, z0[r]);
            z1[r] = vfma2(wa, sa1, z1[r]); z1[r] = vfma2(wb, sb1, z1[r]);
            z2[r] = vfma2(wa, sa2, z2[r]); z2[r] = vfma2(wb, sb2, z2[r]);
        }
    }
    float za[HH], zb[HH], zc[HH];
    #pragma unroll
    for (int r = 0; r < HH; ++r) {
        za[r] = z0[r].x + z0[r].y;
        zb[r] = z1[r].x + z1[r].y;
        zc[r] = z2[r].x + z2[r].y;
    }
    const float b2s = b2[0];
    float v0 = edge_mlp_tail(za, b1, W2, b2s) * (lrow[j0] + CEPS) * invtemp;
    float v1 = edge_mlp_tail(zb, b1, W2, b2s) * (lrow[j1] + CEPS) * invtemp;
    float v2 = edge_mlp_tail(zc, b1, W2, b2s) * (lrow[j2] + CEPS) * invtemp;
    float m = wave_max(fmaxf(fmaxf(v0, v1), v2));
    if ((tid & 63) == 0) red[tid >> 6] = m;
    __syncthreads();
    m = fmaxf(fmaxf(red[0], red[1]), fmaxf(red[2], red[3]));
    float e0 = __expf(v0 - m), e1 = __expf(v1 - m), e2 = __expf(v2 - m);
    float sw = wave_sum(e0 + e1 + e2);
    if ((tid & 63) == 0) red[4 + (tid >> 6)] = sw;
    __syncthreads();
    const float ssum = red[4] + red[5] + red[6] + red[7];
    const float inv = 1.f / ssum;
    float* Er = E2 + (size_t)i * NN;
    const float o0 = e0 * inv, o1 = e1 * inv, o2 = e2 * inv;
    Er[j0] = o0; Er[j1] = o1; Er[j2] = o2;
    if (FUSE) {
        ve2row[j0] = o0; ve2row[j1] = o1; ve2row[j2] = o2;
        __syncthreads();
        const int d = tid & 127, h = tid >> 7;
        v2f accp = {0.f, 0.f}, accx = {0.f, 0.f};
        const int k0 = h * 384;
        #pragma unroll 4
        for (int kk = 0; kk < 384; kk += 2) {
            const int k = k0 + kk;
            v2f sv; sv.x = S[(size_t)k * DD + d]; sv.y = S[(size_t)(k + 1) * DD + d];
            const v2f sev = *(const v2f*)&aux[k];
            const v2f vev = *(const v2f*)&ve2row[k];
            accp = vfma2(sev, sv, accp);
            accx = vfma2(vev, sv, accx);
        }
        part[h][d] = accp.x + accp.y;
        part[2 + h][d] = accx.x + accx.y;
        __syncthreads();
        float preg = 0.f;
        if (tid < DD) {
            preg = part[0][d] + part[1][d];
            const float x = part[2][d] + part[3][d];
            qvv[d] = preg + x;
        }
        __syncthreads();
        {
            v2f acc; acc.x = (h == 0) ? nb[d] : 0.f; acc.y = 0.f;
            const int c0 = h * 64;
            #pragma unroll 4
            for (int c = c0; c < c0 + 64; c += 2) {
                v2f wv; wv.x = WT[(size_t)c * DD + d]; wv.y = WT[(size_t)(c + 1) * DD + d];
                const v2f qq = *(const v2f*)&qvv[c];
                acc = vfma2(qq, wv, acc);
            }
            __syncthreads();
            part[h][d] = acc.x + acc.y;
        }
        __syncthreads();
        float tval = 0.f;
        if (tid < DD) {
            tval = part[0][d] + part[1][d];
            float sm2 = wave_sum(tval);
            if ((tid & 63) == 0) red[tid >> 6] = sm2;
        }
        __syncthreads();
        if (tid < DD) {
            const float mean = (red[0] + red[1]) * (1.f / DD);
            const float dv = tval - mean;
            float s2 = wave_sum(dv * dv);
            if ((tid & 63) == 0) red[4 + (tid >> 6)] = s2;
        }
        __syncthreads();
        if (tid < DD) {
            const float mean = (red[0] + red[1]) * (1.f / DD);
            const float var = (red[4] + red[5]) * (1.f / DD);
            const float ln = (tval - mean) * rsqrtf(var + 1e-5f) * ng[d] + nbeta[d];
            const float val = fmaxf(ln, 0.f) + preg;
            outN[(size_t)i * DD + d] = val;
            outNT[(size_t)d * NN + i] = val;
        }
    }
}

extern "C" void kernel_launch(void* const* d_in, const int* in_sizes, int n_in, void* d_out,
                              int out_size, void* d_ws, size_t ws_size, hipStream_t stream) {
    const float* visual    = (const float*)d_in[0];
    const float* semantic  = (const float*)d_in[1];
    const float* attribute = (const float*)d_in[2];
    const float* Wvn  = (const float*)d_in[3];
    const float* bvn  = (const float*)d_in[4];
    const float* gvn  = (const float*)d_in[5];
    const float* betavn = (const float*)d_in[6];
    const float* Wve1 = (const float*)d_in[7];
    const float* bve1 = (const float*)d_in[8];
    const float* Wve2 = (const float*)d_in[9];
    const float* bve2 = (const float*)d_in[10];
    const float* Wsn  = (const float*)d_in[11];
    const float* bsn  = (const float*)d_in[12];
    const float* gsn  = (const float*)d_in[13];
    const float* betasn = (const float*)d_in[14];
    const float* Wse1 = (const float*)d_in[15];
    const float* bse1 = (const float*)d_in[16];
    const float* Wse2 = (const float*)d_in[17];
    const float* bse2 = (const float*)d_in[18];

    float* out = (float*)d_out;
    float* vp  = out;              // 768*128
    float* sp  = out + 98304;      // 768*128
    float* ve2 = out + 196608;     // 768*768
    float* se2 = out + 786432;     // 768*768

    float* ws   = (float*)d_ws;
    float* simv = ws;              // 768*768 raw logits (already /temp)
    float* sima = ws + 589824;     // 768*768
    float* vpT  = ws + 1179648;    // 128*768
    float* spT  = ws + 1277952;    // 128*768
    float* WvnT = ws + 1376256;    // 128*128
    float* WsnT = ws + 1392640;    // 128*128

    gram_prep_kernel<<<1184, 256, 0, stream>>>(visual, attribute, Wvn, Wsn, simv, sima, WvnT,
                                               WsnT);
    node1_kernel<<<NN / 2, 512, 0, stream>>>(visual, simv, sima, WvnT, bvn, gvn, betavn, vp,
                                             vpT);
    // K3: edge1 (ve2) fused with node2 (sp, spT)
    edge_fused_kernel<true><<<NN, 256, 0, stream>>>(vp, vpT, simv, Wve1, bve1, Wve2, bve2,
                                                    0.1f, ve2, sima, semantic, WsnT, bsn, gsn,
                                                    betasn, sp, spT);
    // K4: edge2 (se2)
    edge_fused_kernel<false><<<NN, 256, 0, stream>>>(sp, spT, sima, Wse1, bse1, Wse2, bse2,
                                                     0.1f, se2, sima, semantic, WsnT, bsn, gsn,
                                                     betasn, nullptr, nullptr);
}